// Round 1
// baseline (1310.663 us; speedup 1.0000x reference)
//
#include <hip/hip_runtime.h>
#include <math.h>

// ---------------------------------------------------------------------------
// DynamicBalancedMarginInnerProduct (ArcFace-style dynamic margin), fp32.
// Outputs (flat, in order): cos[B*C], marginal_logits[B*C],
//   avg_theta, min_theta, max_theta, stdv_theta, avg_w_norm, avg_x_norm
// Pipeline:
//   1) row_norms(feat)    -> norm_f[B], inv_nf[B]        (ws)
//   2) row_norms(weights) -> norm_w[C], inv_nw[C]        (ws)
//   3) SGEMM cos[b,c] = dot(feat[b],W[c]) * inv_nf[b] * inv_nw[c]
//      fused epilogue also writes marginal = 30*cos
//   4) stats_fixup: gather target cos, thetas, deterministic block
//      reductions (max/min/mean/std ddof=1), margin logic, scatter the
//      1024 marginal targets, write 6 scalars + the two avg norms.
// No atomics -> deterministic. ws usage: (2*B + 2*C) floats = ~808 KB.
// ---------------------------------------------------------------------------

#define SCALE_S 30.0f
#define RAD2DEG 57.29577951308232f
#define DEG2RAD 0.017453292519943295f

__global__ __launch_bounds__(64) void row_norms_kernel(
    const float* __restrict__ X, int K,
    float* __restrict__ nrm, float* __restrict__ inv) {
  const int row = blockIdx.x;
  const float* r = X + (size_t)row * K;
  const int t = threadIdx.x;
  float s = 0.f;
  for (int k = t * 4; k < K; k += 64 * 4) {
    float4 v = *(const float4*)(r + k);
    s += v.x * v.x + v.y * v.y + v.z * v.z + v.w * v.w;
  }
#pragma unroll
  for (int off = 32; off > 0; off >>= 1) s += __shfl_down(s, off);
  if (t == 0) {
    float n = sqrtf(s);
    nrm[row] = n;
    inv[row] = 1.0f / n;
  }
}

// Register-blocked fp32 SGEMM: C = A * W^T (both row-major, K contiguous).
// BM=BN=128, BK=16, 256 threads, 8x8 register tile per thread
// (rows {tm..tm+3, tm+64..tm+67}, cols {tn..tn+3, tn+64..tn+67}).
#define BM 128
#define BN 128
#define BK 16

__global__ __launch_bounds__(256) void sgemm_cos_kernel(
    const float* __restrict__ A,   // [M][K]
    const float* __restrict__ W,   // [Cn][K]
    const float* __restrict__ inv_nf, const float* __restrict__ inv_nw,
    float* __restrict__ cosO, float* __restrict__ margO,
    int M, int Cn, int K) {
  __shared__ float As[BK][BM + 4];   // +4 pad: 2-way banks max (free)
  __shared__ float Bs[BK][BN + 4];

  const int t = threadIdx.x;
  const int bm = blockIdx.y * BM;
  const int bn = blockIdx.x * BN;

  // staging role: thread loads rows (lr, lr+64), k-quad lc
  const int lr = t >> 2;          // 0..63
  const int lc = (t & 3) * 4;     // 0,4,8,12
  // compute role
  const int tm = (t & 15) * 4;    // m tile base (and +64)
  const int tn = (t >> 4) * 4;    // n tile base (and +64)

  float acc[8][8];
#pragma unroll
  for (int i = 0; i < 8; ++i)
#pragma unroll
    for (int j = 0; j < 8; ++j) acc[i][j] = 0.f;

  for (int k0 = 0; k0 < K; k0 += BK) {
    float4 a0 = *(const float4*)(A + (size_t)(bm + lr) * K + k0 + lc);
    float4 a1 = *(const float4*)(A + (size_t)(bm + lr + 64) * K + k0 + lc);
    const int wr0 = bn + lr, wr1 = bn + lr + 64;
    float4 b0 = make_float4(0.f, 0.f, 0.f, 0.f);
    float4 b1 = make_float4(0.f, 0.f, 0.f, 0.f);
    if (wr0 < Cn) b0 = *(const float4*)(W + (size_t)wr0 * K + k0 + lc);
    if (wr1 < Cn) b1 = *(const float4*)(W + (size_t)wr1 * K + k0 + lc);

    __syncthreads();  // previous tile fully consumed
    As[lc + 0][lr] = a0.x; As[lc + 1][lr] = a0.y;
    As[lc + 2][lr] = a0.z; As[lc + 3][lr] = a0.w;
    As[lc + 0][lr + 64] = a1.x; As[lc + 1][lr + 64] = a1.y;
    As[lc + 2][lr + 64] = a1.z; As[lc + 3][lr + 64] = a1.w;
    Bs[lc + 0][lr] = b0.x; Bs[lc + 1][lr] = b0.y;
    Bs[lc + 2][lr] = b0.z; Bs[lc + 3][lr] = b0.w;
    Bs[lc + 0][lr + 64] = b1.x; Bs[lc + 1][lr + 64] = b1.y;
    Bs[lc + 2][lr + 64] = b1.z; Bs[lc + 3][lr + 64] = b1.w;
    __syncthreads();

#pragma unroll
    for (int kk = 0; kk < BK; ++kk) {
      float a[8], b[8];
      *(float4*)&a[0] = *(const float4*)&As[kk][tm];
      *(float4*)&a[4] = *(const float4*)&As[kk][tm + 64];
      *(float4*)&b[0] = *(const float4*)&Bs[kk][tn];
      *(float4*)&b[4] = *(const float4*)&Bs[kk][tn + 64];
#pragma unroll
      for (int i = 0; i < 8; ++i)
#pragma unroll
        for (int j = 0; j < 8; ++j) acc[i][j] += a[i] * b[j];
    }
  }

  // epilogue: scale by inv norms, write cos and 30*cos
  float4 wv[2];
  bool full[2];
#pragma unroll
  for (int g = 0; g < 2; ++g) {
    const int n = bn + tn + g * 64;
    full[g] = (n + 3 < Cn);
    if (full[g]) wv[g] = *(const float4*)(inv_nw + n);
  }
#pragma unroll
  for (int i = 0; i < 8; ++i) {
    const int m = bm + tm + ((i < 4) ? i : 60 + i);  // tm+i  /  tm+64+(i-4)
    const float fi = inv_nf[m];
    const size_t rowOff = (size_t)m * Cn;
#pragma unroll
    for (int g = 0; g < 2; ++g) {
      const int n = bn + tn + g * 64;
      if (full[g]) {
        float4 v;
        v.x = acc[i][g * 4 + 0] * fi * wv[g].x;
        v.y = acc[i][g * 4 + 1] * fi * wv[g].y;
        v.z = acc[i][g * 4 + 2] * fi * wv[g].z;
        v.w = acc[i][g * 4 + 3] * fi * wv[g].w;
        *(float4*)(cosO + rowOff + n) = v;
        float4 s;
        s.x = SCALE_S * v.x; s.y = SCALE_S * v.y;
        s.z = SCALE_S * v.z; s.w = SCALE_S * v.w;
        *(float4*)(margO + rowOff + n) = s;
      } else {
#pragma unroll
        for (int q = 0; q < 4; ++q) {
          const int nn = n + q;
          if (nn < Cn) {
            float v = acc[i][g * 4 + q] * fi * inv_nw[nn];
            cosO[rowOff + nn] = v;
            margO[rowOff + nn] = SCALE_S * v;
          }
        }
      }
    }
  }
}

// One block of B(=1024) threads. Deterministic LDS tree reductions.
__global__ __launch_bounds__(1024) void stats_fixup_kernel(
    const float* __restrict__ cosO, float* __restrict__ margO,
    const int* __restrict__ label,
    const float* __restrict__ norm_f, const float* __restrict__ norm_w,
    float* __restrict__ scal, int B, int Cn, int Wn) {
  __shared__ float red[1024];
  __shared__ float s_stat[4];  // max, min, avg, (spare)
  const int t = threadIdx.x;

  const int lb = label[t];
  float tc = cosO[(size_t)t * Cn + lb];
  tc = fminf(1.0f, fmaxf(-1.0f, tc));
  const float theta = acosf(tc) * RAD2DEG;

  // --- sum(theta) ---
  red[t] = theta; __syncthreads();
  for (int s = 512; s > 0; s >>= 1) {
    if (t < s) red[t] += red[t + s];
    __syncthreads();
  }
  if (t == 0) s_stat[2] = red[0] / (float)B;
  __syncthreads();
  const float avg = s_stat[2];
  __syncthreads();

  // --- max(theta) ---
  red[t] = theta; __syncthreads();
  for (int s = 512; s > 0; s >>= 1) {
    if (t < s) red[t] = fmaxf(red[t], red[t + s]);
    __syncthreads();
  }
  if (t == 0) s_stat[0] = red[0];
  __syncthreads();
  const float mx = s_stat[0];
  __syncthreads();

  // --- min(theta) ---
  red[t] = theta; __syncthreads();
  for (int s = 512; s > 0; s >>= 1) {
    if (t < s) red[t] = fminf(red[t], red[t + s]);
    __syncthreads();
  }
  if (t == 0) s_stat[1] = red[0];
  __syncthreads();
  const float mn = s_stat[1];
  __syncthreads();

  // --- sum((theta-avg)^2), ddof=1 ---
  {
    const float d = theta - avg;
    red[t] = d * d;
  }
  __syncthreads();
  for (int s = 512; s > 0; s >>= 1) {
    if (t < s) red[t] += red[t + s];
    __syncthreads();
  }
  const float stdv = sqrtf(red[0] / (float)(B - 1));
  __syncthreads();

  // --- margin logic + scatter fixup ---
  const float margin_above = (mx < 90.0f) ? (90.0f - avg) * DEG2RAD : 0.0f;
  const float margin_below = mn * DEG2RAD;
  const float the_margin = (theta > avg) ? margin_above : margin_below;
  const bool in_range = tc > -cosf(the_margin);
  const float margin_add = in_range ? the_margin : 0.0f;
  const float margin_ext = in_range ? 0.0f : -the_margin * sinf(the_margin);
  const float tmarg = cosf(acosf(tc) + margin_add) + margin_ext;
  margO[(size_t)t * Cn + lb] = SCALE_S * tmarg;

  // --- avg_w_norm over Wn (grid-stride partials, deterministic tree) ---
  float pw = 0.f;
  for (int i = t; i < Wn; i += 1024) pw += norm_w[i];
  red[t] = pw; __syncthreads();
  for (int s = 512; s > 0; s >>= 1) {
    if (t < s) red[t] += red[t + s];
    __syncthreads();
  }
  const float avg_w = red[0] / (float)Wn;
  __syncthreads();

  // --- avg_x_norm over B ---
  red[t] = norm_f[t]; __syncthreads();
  for (int s = 512; s > 0; s >>= 1) {
    if (t < s) red[t] += red[t + s];
    __syncthreads();
  }
  const float avg_x = red[0] / (float)B;

  if (t == 0) {
    scal[0] = avg;
    scal[1] = mn;
    scal[2] = mx;
    scal[3] = stdv;
    scal[4] = avg_w;
    scal[5] = avg_x;
  }
}

extern "C" void kernel_launch(void* const* d_in, const int* in_sizes, int n_in,
                              void* d_out, int out_size, void* d_ws, size_t ws_size,
                              hipStream_t stream) {
  const float* feat = (const float*)d_in[0];
  const int* label = (const int*)d_in[1];
  const float* W = (const float*)d_in[2];

  const int B = in_sizes[1];            // 1024
  const int K = in_sizes[0] / B;        // 512
  const int Cn = in_sizes[2] / K;       // 100000

  float* cosO = (float*)d_out;
  float* margO = cosO + (size_t)B * Cn;
  float* scal = margO + (size_t)B * Cn;

  float* norm_f = (float*)d_ws;
  float* inv_nf = norm_f + B;
  float* norm_w = inv_nf + B;
  float* inv_nw = norm_w + Cn;

  row_norms_kernel<<<B, 64, 0, stream>>>(feat, K, norm_f, inv_nf);
  row_norms_kernel<<<Cn, 64, 0, stream>>>(W, K, norm_w, inv_nw);

  dim3 grid((Cn + BN - 1) / BN, B / BM);
  sgemm_cos_kernel<<<grid, 256, 0, stream>>>(feat, W, inv_nf, inv_nw,
                                             cosO, margO, B, Cn, K);

  stats_fixup_kernel<<<1, B, 0, stream>>>(cosO, margO, label, norm_f, norm_w,
                                          scal, B, Cn, Cn);
}

// Round 2
// 632.875 us; speedup vs baseline: 2.0710x; 2.0710x over previous
//
#include <hip/hip_runtime.h>
#include <math.h>

// ---------------------------------------------------------------------------
// DynamicBalancedMarginInnerProduct — R2: f16-MFMA GEMM (fp32 accumulate).
// Pipeline:
//   1) row_norms(feat)  -> norm_f[B], inv_nf[B]
//   2) row_norms(W)     -> norm_w[C], inv_nw[C]
//   3) gemm_cos_f16: cos[b,c] = (feat[b].W[c]) * inv_nf[b]*inv_nw[c]
//      - 128x128 tile, BK=64, 256 thr (4 waves, each a 64x64 quadrant)
//      - fp32 global -> regs -> cvt f16 -> LINEAR ds_write_b128 with
//        inverse-XOR-permuted global source; ds_read XOR-swizzled (T2 via
//        rule #21: both-sides-or-neither). 2-way read aliasing only (free).
//      - T14: next K-tile's global loads issued before the MFMA phase.
//      - epilogue writes cos and 30*cos (marginal pre-fixup)
//   4) stats_fixup: thetas, deterministic reductions, margin scatter, scalars
// f16 input rounding adds ~1e-4 cos error (~3e-3 on logits) — inside slack.
// ---------------------------------------------------------------------------

typedef _Float16 f16x8 __attribute__((ext_vector_type(8)));
typedef float f32x4 __attribute__((ext_vector_type(4)));

#define SCALE_S 30.0f
#define RAD2DEG 57.29577951308232f
#define DEG2RAD 0.017453292519943295f

__global__ __launch_bounds__(64) void row_norms_kernel(
    const float* __restrict__ X, int K,
    float* __restrict__ nrm, float* __restrict__ inv) {
  const int row = blockIdx.x;
  const float* r = X + (size_t)row * K;
  const int t = threadIdx.x;
  float s = 0.f;
  for (int k = t * 4; k < K; k += 64 * 4) {
    float4 v = *(const float4*)(r + k);
    s += v.x * v.x + v.y * v.y + v.z * v.z + v.w * v.w;
  }
#pragma unroll
  for (int off = 32; off > 0; off >>= 1) s += __shfl_down(s, off);
  if (t == 0) {
    float n = sqrtf(s);
    nrm[row] = n;
    inv[row] = 1.0f / n;
  }
}

// ---------------------------------------------------------------------------
// f16 MFMA GEMM with fused cos/marginal epilogue.
// BM=BN=128, BKE=64 (64 k-elems per LDS tile). LDS = 2 x 16 KB.
// Chunk layout: tile = 1024 chunks of 8 f16 (16 B). Chunk c holds logical
// (row = c>>3, kchunk = (c&7) ^ (row&7)).  Writer: thread t, phase j writes
// chunk c = t + 256*j at LDS byte 16*c (fully contiguous b128 writes,
// conflict-free) and loads the matching permuted 32 B from global (same
// 256 B row segment -> still coalesced).  Reader: lane reads row r,
// kchunk kc at halfs r*64 + ((kc ^ (r&7))*8) -> 2-way bank alias only.
// ---------------------------------------------------------------------------
#define BM 128
#define BN 128
#define BKE 64

__global__ __launch_bounds__(256) void gemm_cos_f16(
    const float* __restrict__ A,   // [M][K] fp32
    const float* __restrict__ W,   // [Cn][K] fp32
    const float* __restrict__ inv_nf, const float* __restrict__ inv_nw,
    float* __restrict__ cosO, float* __restrict__ margO,
    int M, int Cn, int K) {
  __shared__ __align__(16) _Float16 Ash[BM * BKE];  // 16 KB
  __shared__ __align__(16) _Float16 Wsh[BN * BKE];  // 16 KB

  const int t = threadIdx.x;
  const int bm = blockIdx.x * BM;   // x = row-blocks (fastest) -> W panel shared
  const int bn = blockIdx.y * BN;
  const int lane = t & 63;
  const int wid = t >> 6;
  const int wm = (wid >> 1) * 64;   // wave's 64x64 quadrant
  const int wn = (wid & 1) * 64;
  const int lrow = lane >> 4;       // 0..3
  const int lcol = lane & 15;       // 0..15

  // staging geometry (per phase j=0..3)
  int srow[4], skc[4];
#pragma unroll
  for (int j = 0; j < 4; ++j) {
    const int c = t + 256 * j;
    srow[j] = c >> 3;                     // 0..127
    skc[j] = (t & 7) ^ (srow[j] & 7);     // inverse-permuted source kchunk
  }

  f32x4 acc[4][4];
#pragma unroll
  for (int m = 0; m < 4; ++m)
#pragma unroll
    for (int n = 0; n < 4; ++n) acc[m][n] = (f32x4)0.f;

  float4 ra[4][2], rw[4][2];

  // prologue: load K-tile 0 into regs
#pragma unroll
  for (int j = 0; j < 4; ++j) {
    const float* ap = A + (size_t)(bm + srow[j]) * K + skc[j] * 8;
    ra[j][0] = *(const float4*)ap;
    ra[j][1] = *(const float4*)(ap + 4);
    const int wr = bn + srow[j];
    if (wr < Cn) {
      const float* wp = W + (size_t)wr * K + skc[j] * 8;
      rw[j][0] = *(const float4*)wp;
      rw[j][1] = *(const float4*)(wp + 4);
    } else {
      rw[j][0] = make_float4(0.f, 0.f, 0.f, 0.f);
      rw[j][1] = make_float4(0.f, 0.f, 0.f, 0.f);
    }
  }

  const int nstep = K / BKE;
  for (int s = 0; s < nstep; ++s) {
    __syncthreads();  // all waves done reading LDS from previous step
    // cvt + linear conflict-free ds_write_b128
#pragma unroll
    for (int j = 0; j < 4; ++j) {
      const int c = t + 256 * j;
      f16x8 ha, hw;
#pragma unroll
      for (int q = 0; q < 4; ++q) {
        ha[q]     = (_Float16)((&ra[j][0].x)[q]);
        ha[4 + q] = (_Float16)((&ra[j][1].x)[q]);
        hw[q]     = (_Float16)((&rw[j][0].x)[q]);
        hw[4 + q] = (_Float16)((&rw[j][1].x)[q]);
      }
      *(f16x8*)(Ash + c * 8) = ha;
      *(f16x8*)(Wsh + c * 8) = hw;
    }
    __syncthreads();

    // T14: issue next K-tile's global loads before compute
    if (s + 1 < nstep) {
      const int k0 = (s + 1) * BKE;
#pragma unroll
      for (int j = 0; j < 4; ++j) {
        const float* ap = A + (size_t)(bm + srow[j]) * K + k0 + skc[j] * 8;
        ra[j][0] = *(const float4*)ap;
        ra[j][1] = *(const float4*)(ap + 4);
        const int wr = bn + srow[j];
        if (wr < Cn) {
          const float* wp = W + (size_t)wr * K + k0 + skc[j] * 8;
          rw[j][0] = *(const float4*)wp;
          rw[j][1] = *(const float4*)(wp + 4);
        } else {
          rw[j][0] = make_float4(0.f, 0.f, 0.f, 0.f);
          rw[j][1] = make_float4(0.f, 0.f, 0.f, 0.f);
        }
      }
    }

    // compute: 2 x (8 swizzled ds_read_b128 + 16 MFMA)
#pragma unroll
    for (int ks = 0; ks < 2; ++ks) {
      f16x8 af[4], bf[4];
      const int kc = ks * 4 + lrow;
#pragma unroll
      for (int m = 0; m < 4; ++m) {
        const int rowa = wm + m * 16 + lcol;
        af[m] = *(const f16x8*)(Ash + rowa * 64 + ((kc ^ (rowa & 7)) * 8));
        const int rowb = wn + m * 16 + lcol;
        bf[m] = *(const f16x8*)(Wsh + rowb * 64 + ((kc ^ (rowb & 7)) * 8));
      }
#pragma unroll
      for (int m = 0; m < 4; ++m)
#pragma unroll
        for (int n = 0; n < 4; ++n)
          acc[m][n] = __builtin_amdgcn_mfma_f32_16x16x32_f16(
              af[m], bf[n], acc[m][n], 0, 0, 0);
    }
  }

  // epilogue: scale by inverse norms; write cos and 30*cos
  float fi[4][4];
#pragma unroll
  for (int m = 0; m < 4; ++m)
#pragma unroll
    for (int r = 0; r < 4; ++r)
      fi[m][r] = inv_nf[bm + wm + m * 16 + lrow * 4 + r];

#pragma unroll
  for (int n = 0; n < 4; ++n) {
    const int col = bn + wn + n * 16 + lcol;
    const bool cv = col < Cn;
    const float wiv = cv ? inv_nw[col] : 0.f;
#pragma unroll
    for (int m = 0; m < 4; ++m) {
      const int row0 = bm + wm + m * 16 + lrow * 4;
#pragma unroll
      for (int r = 0; r < 4; ++r) {
        if (cv) {
          const float v = acc[m][n][r] * fi[m][r] * wiv;
          const size_t o = (size_t)(row0 + r) * Cn + col;
          cosO[o] = v;
          margO[o] = SCALE_S * v;
        }
      }
    }
  }
}

// One block of B(=1024) threads. Deterministic LDS tree reductions.
__global__ __launch_bounds__(1024) void stats_fixup_kernel(
    const float* __restrict__ cosO, float* __restrict__ margO,
    const int* __restrict__ label,
    const float* __restrict__ norm_f, const float* __restrict__ norm_w,
    float* __restrict__ scal, int B, int Cn, int Wn) {
  __shared__ float red[1024];
  __shared__ float s_stat[4];
  const int t = threadIdx.x;

  const int lb = label[t];
  float tc = cosO[(size_t)t * Cn + lb];
  tc = fminf(1.0f, fmaxf(-1.0f, tc));
  const float theta = acosf(tc) * RAD2DEG;

  red[t] = theta; __syncthreads();
  for (int s = 512; s > 0; s >>= 1) {
    if (t < s) red[t] += red[t + s];
    __syncthreads();
  }
  if (t == 0) s_stat[2] = red[0] / (float)B;
  __syncthreads();
  const float avg = s_stat[2];
  __syncthreads();

  red[t] = theta; __syncthreads();
  for (int s = 512; s > 0; s >>= 1) {
    if (t < s) red[t] = fmaxf(red[t], red[t + s]);
    __syncthreads();
  }
  if (t == 0) s_stat[0] = red[0];
  __syncthreads();
  const float mx = s_stat[0];
  __syncthreads();

  red[t] = theta; __syncthreads();
  for (int s = 512; s > 0; s >>= 1) {
    if (t < s) red[t] = fminf(red[t], red[t + s]);
    __syncthreads();
  }
  if (t == 0) s_stat[1] = red[0];
  __syncthreads();
  const float mn = s_stat[1];
  __syncthreads();

  {
    const float d = theta - avg;
    red[t] = d * d;
  }
  __syncthreads();
  for (int s = 512; s > 0; s >>= 1) {
    if (t < s) red[t] += red[t + s];
    __syncthreads();
  }
  const float stdv = sqrtf(red[0] / (float)(B - 1));
  __syncthreads();

  const float margin_above = (mx < 90.0f) ? (90.0f - avg) * DEG2RAD : 0.0f;
  const float margin_below = mn * DEG2RAD;
  const float the_margin = (theta > avg) ? margin_above : margin_below;
  const bool in_range = tc > -cosf(the_margin);
  const float margin_add = in_range ? the_margin : 0.0f;
  const float margin_ext = in_range ? 0.0f : -the_margin * sinf(the_margin);
  const float tmarg = cosf(acosf(tc) + margin_add) + margin_ext;
  margO[(size_t)t * Cn + lb] = SCALE_S * tmarg;

  float pw = 0.f;
  for (int i = t; i < Wn; i += 1024) pw += norm_w[i];
  red[t] = pw; __syncthreads();
  for (int s = 512; s > 0; s >>= 1) {
    if (t < s) red[t] += red[t + s];
    __syncthreads();
  }
  const float avg_w = red[0] / (float)Wn;
  __syncthreads();

  red[t] = norm_f[t]; __syncthreads();
  for (int s = 512; s > 0; s >>= 1) {
    if (t < s) red[t] += red[t + s];
    __syncthreads();
  }
  const float avg_x = red[0] / (float)B;

  if (t == 0) {
    scal[0] = avg;
    scal[1] = mn;
    scal[2] = mx;
    scal[3] = stdv;
    scal[4] = avg_w;
    scal[5] = avg_x;
  }
}

extern "C" void kernel_launch(void* const* d_in, const int* in_sizes, int n_in,
                              void* d_out, int out_size, void* d_ws, size_t ws_size,
                              hipStream_t stream) {
  const float* feat = (const float*)d_in[0];
  const int* label = (const int*)d_in[1];
  const float* W = (const float*)d_in[2];

  const int B = in_sizes[1];            // 1024
  const int K = in_sizes[0] / B;        // 512
  const int Cn = in_sizes[2] / K;       // 100000

  float* cosO = (float*)d_out;
  float* margO = cosO + (size_t)B * Cn;
  float* scal = margO + (size_t)B * Cn;

  float* norm_f = (float*)d_ws;
  float* inv_nf = norm_f + B;
  float* norm_w = inv_nf + B;
  float* inv_nw = norm_w + Cn;

  row_norms_kernel<<<B, 64, 0, stream>>>(feat, K, norm_f, inv_nf);
  row_norms_kernel<<<Cn, 64, 0, stream>>>(W, K, norm_w, inv_nw);

  dim3 grid(B / BM, (Cn + BN - 1) / BN);  // x = row-blocks (fastest)
  gemm_cos_f16<<<grid, 256, 0, stream>>>(feat, W, inv_nf, inv_nw,
                                         cosO, margO, B, Cn, K);

  stats_fixup_kernel<<<1, B, 0, stream>>>(cosO, margO, label, norm_f, norm_w,
                                          scal, B, Cn, Cn);
}

// Round 3
// 371.658 us; speedup vs baseline: 3.5265x; 1.7028x over previous
//
#include <hip/hip_runtime.h>
#include <math.h>
#include <stdint.h>

// ---------------------------------------------------------------------------
// DynamicBalancedMarginInnerProduct — R3.
//   1) norm_cvt(feat) -> norm_f/inv_nf + A16 (f16, row-major)      [ws]
//   2) norm_cvt(W)    -> norm_w/inv_nw + W16 (f16, zero-padded)    [ws]
//   3) gemm_cos_lds: m97 structure — global_load_lds width 16 with
//      per-lane pre-swizzled SOURCE + linear LDS dest + XOR-swizzled
//      ds_read_b128 (conflict-free, verified 0 in R2). XCD-bijective
//      block swizzle, rows-fastest within an XCD chunk -> W panel
//      fetched ~once per XCD L2. Nontemporal epilogue stores.
//   4) stats_fixup: deterministic reductions + margin scatter.
// Fallback (ws too small): R2 reg-staged kernel + XCD swizzle.
// ---------------------------------------------------------------------------

typedef _Float16 f16x8 __attribute__((ext_vector_type(8)));
typedef float f32x4 __attribute__((ext_vector_type(4)));

#define SCALE_S 30.0f
#define RAD2DEG 57.29577951308232f
#define DEG2RAD 0.017453292519943295f

#define GL16(g, l)                                                    \
  __builtin_amdgcn_global_load_lds(                                   \
      (const __attribute__((address_space(1))) void*)(g),             \
      (__attribute__((address_space(3))) void*)(l), 16, 0, 0)

// --- fused row-norm + f16 convert (+ zero-pad rows >= Cn) ------------------
__global__ __launch_bounds__(64) void norm_cvt_kernel(
    const float* __restrict__ X, _Float16* __restrict__ X16, int K, int Cn,
    float* __restrict__ nrm, float* __restrict__ inv) {
  const int row = blockIdx.x;
  const int t = threadIdx.x;
  _Float16* o = X16 + (size_t)row * K;
  if (row >= Cn) {
    for (int k = t * 8; k < K; k += 64 * 8)
      *(f16x8*)(o + k) = (f16x8)(_Float16)0.f;
    return;
  }
  const float* r = X + (size_t)row * K;
  float s = 0.f;
  for (int k = t * 8; k < K; k += 64 * 8) {
    float4 v0 = *(const float4*)(r + k);
    float4 v1 = *(const float4*)(r + k + 4);
    s += v0.x * v0.x + v0.y * v0.y + v0.z * v0.z + v0.w * v0.w +
         v1.x * v1.x + v1.y * v1.y + v1.z * v1.z + v1.w * v1.w;
    f16x8 h;
    h[0] = (_Float16)v0.x; h[1] = (_Float16)v0.y;
    h[2] = (_Float16)v0.z; h[3] = (_Float16)v0.w;
    h[4] = (_Float16)v1.x; h[5] = (_Float16)v1.y;
    h[6] = (_Float16)v1.z; h[7] = (_Float16)v1.w;
    *(f16x8*)(o + k) = h;
  }
#pragma unroll
  for (int off = 32; off > 0; off >>= 1) s += __shfl_down(s, off);
  if (t == 0) {
    float n = sqrtf(s);
    nrm[row] = n;
    inv[row] = 1.0f / n;
  }
}

__global__ __launch_bounds__(64) void row_norms_kernel(
    const float* __restrict__ X, int K,
    float* __restrict__ nrm, float* __restrict__ inv) {
  const int row = blockIdx.x;
  const float* r = X + (size_t)row * K;
  const int t = threadIdx.x;
  float s = 0.f;
  for (int k = t * 4; k < K; k += 64 * 4) {
    float4 v = *(const float4*)(r + k);
    s += v.x * v.x + v.y * v.y + v.z * v.z + v.w * v.w;
  }
#pragma unroll
  for (int off = 32; off > 0; off >>= 1) s += __shfl_down(s, off);
  if (t == 0) {
    float n = sqrtf(s);
    nrm[row] = n;
    inv[row] = 1.0f / n;
  }
}

// --- fast GEMM: f16 inputs from ws, global_load_lds staging ----------------
// Tile 128x128, BK=64 halfs. LDS image: 1024 chunks of 8 halfs; chunk c
// holds (row=c>>3, kchunk=(c&7)^(row&7)). Staged linearly (wave w owns
// slots w*4..w*4+3, 1024B each); per-lane SOURCE address carries the
// permutation. Reader XORs the same involution -> 2-way alias only.
__global__ __launch_bounds__(256) void gemm_cos_lds(
    const _Float16* __restrict__ A16, const _Float16* __restrict__ W16,
    const float* __restrict__ inv_nf, const float* __restrict__ inv_nw,
    float* __restrict__ cosO, float* __restrict__ margO,
    int Cn, int npanel) {
  __shared__ __align__(16) _Float16 Ash[128 * 64];
  __shared__ __align__(16) _Float16 Wsh[128 * 64];
  const int K = 512;

  // XCD-bijective swizzle (nblk % 8 == 0), rows-fastest within chunk
  const int nblk = npanel * 8;
  const int lin = blockIdx.x;
  const int q = nblk >> 3;
  const int wg = (lin & 7) * q + (lin >> 3);
  const int bm = (wg & 7) * 128;
  const int bn = (wg >> 3) * 128;

  const int t = threadIdx.x;
  const int lane = t & 63;
  const int w = t >> 6;
  const int wm = (w >> 1) * 64;
  const int wn = (w & 1) * 64;
  const int lrow = lane >> 4;
  const int lcol = lane & 15;

  const _Float16* srcA[4];
  const _Float16* srcW[4];
  _Float16* dstA[4];
  _Float16* dstW[4];
#pragma unroll
  for (int i = 0; i < 4; ++i) {
    const int slot = w * 4 + i;
    const int c = slot * 64 + lane;
    const int row = c >> 3;
    const int kc = (c & 7) ^ (row & 7);
    srcA[i] = A16 + (size_t)(bm + row) * K + kc * 8;
    srcW[i] = W16 + (size_t)(bn + row) * K + kc * 8;
    dstA[i] = Ash + slot * 512;  // wave-uniform: slot depends only on w
    dstW[i] = Wsh + slot * 512;
  }

  f32x4 acc[4][4];
#pragma unroll
  for (int m = 0; m < 4; ++m)
#pragma unroll
    for (int n = 0; n < 4; ++n) acc[m][n] = (f32x4)0.f;

  for (int s = 0; s < 8; ++s) {
    __syncthreads();  // prior LDS reads complete before overwrite
#pragma unroll
    for (int i = 0; i < 4; ++i) {
      GL16(srcA[i], dstA[i]);
      GL16(srcW[i], dstW[i]);
      srcA[i] += 64;
      srcW[i] += 64;
    }
    __syncthreads();  // compiler drains vmcnt before s_barrier

#pragma unroll
    for (int ks = 0; ks < 2; ++ks) {
      f16x8 af[4], bf[4];
      const int kc = ks * 4 + lrow;
#pragma unroll
      for (int m = 0; m < 4; ++m) {
        const int rowa = wm + m * 16 + lcol;
        af[m] = *(const f16x8*)(Ash + rowa * 64 + ((kc ^ (rowa & 7)) * 8));
        const int rowb = wn + m * 16 + lcol;
        bf[m] = *(const f16x8*)(Wsh + rowb * 64 + ((kc ^ (rowb & 7)) * 8));
      }
#pragma unroll
      for (int m = 0; m < 4; ++m)
#pragma unroll
        for (int n = 0; n < 4; ++n)
          acc[m][n] = __builtin_amdgcn_mfma_f32_16x16x32_f16(
              af[m], bf[n], acc[m][n], 0, 0, 0);
    }
  }

  float fi[4][4];
#pragma unroll
  for (int m = 0; m < 4; ++m)
#pragma unroll
    for (int r = 0; r < 4; ++r)
      fi[m][r] = inv_nf[bm + wm + m * 16 + lrow * 4 + r];

#pragma unroll
  for (int n = 0; n < 4; ++n) {
    const int col = bn + wn + n * 16 + lcol;
    if (col < Cn) {
      const float wiv = inv_nw[col];
#pragma unroll
      for (int m = 0; m < 4; ++m) {
        const int row0 = bm + wm + m * 16 + lrow * 4;
#pragma unroll
        for (int r = 0; r < 4; ++r) {
          const float v = acc[m][n][r] * fi[m][r] * wiv;
          const size_t o = (size_t)(row0 + r) * Cn + col;
          __builtin_nontemporal_store(v, cosO + o);
          __builtin_nontemporal_store(SCALE_S * v, margO + o);
        }
      }
    }
  }
}

// --- fallback GEMM (R2 reg-staged, + XCD swizzle) --------------------------
__global__ __launch_bounds__(256) void gemm_cos_f16(
    const float* __restrict__ A, const float* __restrict__ W,
    const float* __restrict__ inv_nf, const float* __restrict__ inv_nw,
    float* __restrict__ cosO, float* __restrict__ margO,
    int Cn, int K, int npanel) {
  __shared__ __align__(16) _Float16 Ash[128 * 64];
  __shared__ __align__(16) _Float16 Wsh[128 * 64];

  const int nblk = npanel * 8;
  const int lin = blockIdx.x;
  const int q = nblk >> 3;
  const int wg = (lin & 7) * q + (lin >> 3);
  const int bm = (wg & 7) * 128;
  const int bn = (wg >> 3) * 128;

  const int t = threadIdx.x;
  const int lane = t & 63;
  const int wid = t >> 6;
  const int wm = (wid >> 1) * 64;
  const int wn = (wid & 1) * 64;
  const int lrow = lane >> 4;
  const int lcol = lane & 15;

  int srow[4], skc[4];
#pragma unroll
  for (int j = 0; j < 4; ++j) {
    const int c = t + 256 * j;
    srow[j] = c >> 3;
    skc[j] = (t & 7) ^ (srow[j] & 7);
  }

  f32x4 acc[4][4];
#pragma unroll
  for (int m = 0; m < 4; ++m)
#pragma unroll
    for (int n = 0; n < 4; ++n) acc[m][n] = (f32x4)0.f;

  float4 ra[4][2], rw[4][2];
#pragma unroll
  for (int j = 0; j < 4; ++j) {
    const float* ap = A + (size_t)(bm + srow[j]) * K + skc[j] * 8;
    ra[j][0] = *(const float4*)ap;
    ra[j][1] = *(const float4*)(ap + 4);
    const int wr = bn + srow[j];
    if (wr < Cn) {
      const float* wp = W + (size_t)wr * K + skc[j] * 8;
      rw[j][0] = *(const float4*)wp;
      rw[j][1] = *(const float4*)(wp + 4);
    } else {
      rw[j][0] = make_float4(0.f, 0.f, 0.f, 0.f);
      rw[j][1] = make_float4(0.f, 0.f, 0.f, 0.f);
    }
  }

  const int nstep = K / 64;
  for (int s = 0; s < nstep; ++s) {
    __syncthreads();
#pragma unroll
    for (int j = 0; j < 4; ++j) {
      const int c = t + 256 * j;
      f16x8 ha, hw;
#pragma unroll
      for (int qq = 0; qq < 4; ++qq) {
        ha[qq] = (_Float16)((&ra[j][0].x)[qq]);
        ha[4 + qq] = (_Float16)((&ra[j][1].x)[qq]);
        hw[qq] = (_Float16)((&rw[j][0].x)[qq]);
        hw[4 + qq] = (_Float16)((&rw[j][1].x)[qq]);
      }
      *(f16x8*)(Ash + c * 8) = ha;
      *(f16x8*)(Wsh + c * 8) = hw;
    }
    __syncthreads();

    if (s + 1 < nstep) {
      const int k0 = (s + 1) * 64;
#pragma unroll
      for (int j = 0; j < 4; ++j) {
        const float* ap = A + (size_t)(bm + srow[j]) * K + k0 + skc[j] * 8;
        ra[j][0] = *(const float4*)ap;
        ra[j][1] = *(const float4*)(ap + 4);
        const int wr = bn + srow[j];
        if (wr < Cn) {
          const float* wp = W + (size_t)wr * K + k0 + skc[j] * 8;
          rw[j][0] = *(const float4*)wp;
          rw[j][1] = *(const float4*)(wp + 4);
        } else {
          rw[j][0] = make_float4(0.f, 0.f, 0.f, 0.f);
          rw[j][1] = make_float4(0.f, 0.f, 0.f, 0.f);
        }
      }
    }

#pragma unroll
    for (int ks = 0; ks < 2; ++ks) {
      f16x8 af[4], bf[4];
      const int kc = ks * 4 + lrow;
#pragma unroll
      for (int m = 0; m < 4; ++m) {
        const int rowa = wm + m * 16 + lcol;
        af[m] = *(const f16x8*)(Ash + rowa * 64 + ((kc ^ (rowa & 7)) * 8));
        const int rowb = wn + m * 16 + lcol;
        bf[m] = *(const f16x8*)(Wsh + rowb * 64 + ((kc ^ (rowb & 7)) * 8));
      }
#pragma unroll
      for (int m = 0; m < 4; ++m)
#pragma unroll
        for (int n = 0; n < 4; ++n)
          acc[m][n] = __builtin_amdgcn_mfma_f32_16x16x32_f16(
              af[m], bf[n], acc[m][n], 0, 0, 0);
    }
  }

  float fi[4][4];
#pragma unroll
  for (int m = 0; m < 4; ++m)
#pragma unroll
    for (int r = 0; r < 4; ++r)
      fi[m][r] = inv_nf[bm + wm + m * 16 + lrow * 4 + r];

#pragma unroll
  for (int n = 0; n < 4; ++n) {
    const int col = bn + wn + n * 16 + lcol;
    if (col < Cn) {
      const float wiv = inv_nw[col];
#pragma unroll
      for (int m = 0; m < 4; ++m) {
        const int row0 = bm + wm + m * 16 + lrow * 4;
#pragma unroll
        for (int r = 0; r < 4; ++r) {
          const float v = acc[m][n][r] * fi[m][r] * wiv;
          const size_t o = (size_t)(row0 + r) * Cn + col;
          __builtin_nontemporal_store(v, cosO + o);
          __builtin_nontemporal_store(SCALE_S * v, margO + o);
        }
      }
    }
  }
}

// --- stats + margin scatter ------------------------------------------------
__global__ __launch_bounds__(1024) void stats_fixup_kernel(
    const float* __restrict__ cosO, float* __restrict__ margO,
    const int* __restrict__ label,
    const float* __restrict__ norm_f, const float* __restrict__ norm_w,
    float* __restrict__ scal, int B, int Cn, int Wn) {
  __shared__ float red[1024];
  __shared__ float s_stat[4];
  const int t = threadIdx.x;

  const int lb = label[t];
  float tc = cosO[(size_t)t * Cn + lb];
  tc = fminf(1.0f, fmaxf(-1.0f, tc));
  const float theta = acosf(tc) * RAD2DEG;

  red[t] = theta; __syncthreads();
  for (int s = 512; s > 0; s >>= 1) {
    if (t < s) red[t] += red[t + s];
    __syncthreads();
  }
  if (t == 0) s_stat[2] = red[0] / (float)B;
  __syncthreads();
  const float avg = s_stat[2];
  __syncthreads();

  red[t] = theta; __syncthreads();
  for (int s = 512; s > 0; s >>= 1) {
    if (t < s) red[t] = fmaxf(red[t], red[t + s]);
    __syncthreads();
  }
  if (t == 0) s_stat[0] = red[0];
  __syncthreads();
  const float mx = s_stat[0];
  __syncthreads();

  red[t] = theta; __syncthreads();
  for (int s = 512; s > 0; s >>= 1) {
    if (t < s) red[t] = fminf(red[t], red[t + s]);
    __syncthreads();
  }
  if (t == 0) s_stat[1] = red[0];
  __syncthreads();
  const float mn = s_stat[1];
  __syncthreads();

  {
    const float d = theta - avg;
    red[t] = d * d;
  }
  __syncthreads();
  for (int s = 512; s > 0; s >>= 1) {
    if (t < s) red[t] += red[t + s];
    __syncthreads();
  }
  const float stdv = sqrtf(red[0] / (float)(B - 1));
  __syncthreads();

  const float margin_above = (mx < 90.0f) ? (90.0f - avg) * DEG2RAD : 0.0f;
  const float margin_below = mn * DEG2RAD;
  const float the_margin = (theta > avg) ? margin_above : margin_below;
  const bool in_range = tc > -cosf(the_margin);
  const float margin_add = in_range ? the_margin : 0.0f;
  const float margin_ext = in_range ? 0.0f : -the_margin * sinf(the_margin);
  const float tmarg = cosf(acosf(tc) + margin_add) + margin_ext;
  margO[(size_t)t * Cn + lb] = SCALE_S * tmarg;

  float pw = 0.f;
  for (int i = t; i < Wn; i += 1024) pw += norm_w[i];
  red[t] = pw; __syncthreads();
  for (int s = 512; s > 0; s >>= 1) {
    if (t < s) red[t] += red[t + s];
    __syncthreads();
  }
  const float avg_w = red[0] / (float)Wn;
  __syncthreads();

  red[t] = norm_f[t]; __syncthreads();
  for (int s = 512; s > 0; s >>= 1) {
    if (t < s) red[t] += red[t + s];
    __syncthreads();
  }
  const float avg_x = red[0] / (float)B;

  if (t == 0) {
    scal[0] = avg;
    scal[1] = mn;
    scal[2] = mx;
    scal[3] = stdv;
    scal[4] = avg_w;
    scal[5] = avg_x;
  }
}

extern "C" void kernel_launch(void* const* d_in, const int* in_sizes, int n_in,
                              void* d_out, int out_size, void* d_ws, size_t ws_size,
                              hipStream_t stream) {
  const float* feat = (const float*)d_in[0];
  const int* label = (const int*)d_in[1];
  const float* W = (const float*)d_in[2];

  const int B = in_sizes[1];            // 1024
  const int K = in_sizes[0] / B;        // 512
  const int Cn = in_sizes[2] / K;       // 100000
  const int CnPad = ((Cn + 127) / 128) * 128;  // 100096
  const int npanel = CnPad / 128;

  float* cosO = (float*)d_out;
  float* margO = cosO + (size_t)B * Cn;
  float* scal = margO + (size_t)B * Cn;

  float* norm_f = (float*)d_ws;
  float* inv_nf = norm_f + B;
  float* norm_w = inv_nf + B;
  float* inv_nw = norm_w + CnPad;
  _Float16* A16 = (_Float16*)(inv_nw + CnPad);
  _Float16* W16 = A16 + (size_t)B * K;

  const size_t need = sizeof(float) * (2 * (size_t)B + 2 * (size_t)CnPad) +
                      sizeof(_Float16) * ((size_t)B * K + (size_t)CnPad * K);

  if (ws_size >= need) {
    norm_cvt_kernel<<<B, 64, 0, stream>>>(feat, A16, K, B, norm_f, inv_nf);
    norm_cvt_kernel<<<CnPad, 64, 0, stream>>>(W, W16, K, Cn, norm_w, inv_nw);
    gemm_cos_lds<<<npanel * 8, 256, 0, stream>>>(A16, W16, inv_nf, inv_nw,
                                                 cosO, margO, Cn, npanel);
  } else {
    row_norms_kernel<<<B, 64, 0, stream>>>(feat, K, norm_f, inv_nf);
    row_norms_kernel<<<Cn, 64, 0, stream>>>(W, K, norm_w, inv_nw);
    gemm_cos_f16<<<npanel * 8, 256, 0, stream>>>(feat, W, inv_nf, inv_nw,
                                                 cosO, margO, Cn, K, npanel);
  }

  stats_fixup_kernel<<<1, B, 0, stream>>>(cosO, margO, label, norm_f, norm_w,
                                          scal, B, Cn, Cn);
}